// Round 1
// baseline (183.944 us; speedup 1.0000x reference)
//
#include <hip/hip_runtime.h>
#include <hip/hip_bf16.h>

// B=2, S=2048, D=1024, H=16, DK=64, BAND=100. Inputs f32 (auto-detect; bf16 fallback).
// Output f32. R10: QKV projection ported to 256x256 8-phase counted-vmcnt template
// (T2 st_16x32 swizzle via pre-swizzled gload_lds source, T3+T4 counted vmcnt(4),
// T5 setprio, raw s_barrier -- no vmcnt(0) drain in main loop). N=3072 fused q|k|v.

typedef __attribute__((ext_vector_type(8))) short short8;
typedef __attribute__((ext_vector_type(4))) float f32x4;

#define S_LEN 2048
#define NH 16
#define DK 64
#define BANDW 100

#define X_ELEMS   (2 * S_LEN * 1024)
#define W_ELEMS   (1024 * 1024)
#define QKV_ELEMS (2 * NH * S_LEN * DK)
#define AO_ELEMS  (2 * S_LEN * 1024)

__device__ __attribute__((aligned(256))) short g_X[X_ELEMS];
__device__ __attribute__((aligned(256))) short g_W[4 * W_ELEMS];   // Wq|Wk|Wv|Wo
__device__ __attribute__((aligned(256))) short g_b[4 * 1024];      // bq|bk|bv|bo
__device__ __attribute__((aligned(256))) short g_Q[QKV_ELEMS];     // pre-scaled by 1/8
__device__ __attribute__((aligned(256))) short g_K[QKV_ELEMS];
__device__ __attribute__((aligned(256))) short g_V[QKV_ELEMS];     // row-major [B,H,S,DK]
__device__ __attribute__((aligned(256))) short g_AO[AO_ELEMS];

__device__ __forceinline__ float bf2f(short u) {
    unsigned x = ((unsigned)(unsigned short)u) << 16;
    return __builtin_bit_cast(float, x);
}
__device__ __forceinline__ short f2bf(float f) {
    unsigned x = __builtin_bit_cast(unsigned, f);
    unsigned r = (x + 0x7fffu + ((x >> 16) & 1u)) >> 16;
    return (short)r;
}

#define GLOAD_LDS(gp, lp) \
    __builtin_amdgcn_global_load_lds( \
        (const __attribute__((address_space(1))) void*)(gp), \
        (__attribute__((address_space(3))) void*)(lp), 16, 0, 0)

// ---------------- Fused detect + convert (R9 form) ----------------
#define XC   (X_ELEMS / 8)
#define WC   (W_ELEMS / 8)
#define BC   (1024 / 8)
#define TOTC (XC + 4 * WC + 4 * BC)

__global__ __launch_bounds__(256) void convert_all(
    const void* __restrict__ x,
    const void* __restrict__ w0, const void* __restrict__ b0,
    const void* __restrict__ w1, const void* __restrict__ b1,
    const void* __restrict__ w2, const void* __restrict__ b2,
    const void* __restrict__ w3, const void* __restrict__ b3)
{
    __shared__ int cnt[256];
    {
        const unsigned* xw = (const unsigned*)x;
        int local = 0;
        #pragma unroll
        for (int i = 0; i < 4; i++) {
            unsigned wv = xw[threadIdx.x * 4 + i];
            unsigned e = (wv >> 7) & 0xFF;
            if (e >= 100 && e <= 140) local++;
        }
        cnt[threadIdx.x] = local;
    }
    __syncthreads();
    for (int s = 128; s > 0; s >>= 1) {
        if (threadIdx.x < s) cnt[threadIdx.x] += cnt[threadIdx.x + s];
        __syncthreads();
    }
    const int is_bf16 = (cnt[0] > 512);

    long i = (long)blockIdx.x * 256 + threadIdx.x;
    if (i >= TOTC) return;

    const void* src; short* dst; long off;
    if (i < XC)                { src = x;  dst = g_X;              off = i; }
    else if ((i -= XC) < WC)   { src = w0; dst = g_W + 0L*W_ELEMS; off = i; }
    else if ((i -= WC) < WC)   { src = w1; dst = g_W + 1L*W_ELEMS; off = i; }
    else if ((i -= WC) < WC)   { src = w2; dst = g_W + 2L*W_ELEMS; off = i; }
    else if ((i -= WC) < WC)   { src = w3; dst = g_W + 3L*W_ELEMS; off = i; }
    else if ((i -= WC) < BC)   { src = b0; dst = g_b + 0*1024;     off = i; }
    else if ((i -= BC) < BC)   { src = b1; dst = g_b + 1*1024;     off = i; }
    else if ((i -= BC) < BC)   { src = b2; dst = g_b + 2*1024;     off = i; }
    else                       { src = b3; dst = g_b + 3*1024;     off = i - BC; }

    if (is_bf16) {
        ((short8*)dst)[off] = ((const short8*)src)[off];
    } else {
        const float* s = (const float*)src + off * 8;
        short8 o;
        #pragma unroll
        for (int e = 0; e < 8; e++) o[e] = f2bf(s[e]);
        ((short8*)dst)[off] = o;
    }
}

// ---------------- Fused QKV GEMM: 256x256 tile, BK=64, 8-wave 8-phase ----------------
// M=4096 (B*S), N=3072 (q|k|v), K=1024. Out[m][n] = sum_k X[m][k]*W[n][k].
// LDS: 2 dbuf x {A,B} x 2 halves x [128][64] bf16 = 128 KiB.
// st_16x32 swizzle: LDS byte b holds global data for u = b ^ (((b>>9)&1)<<5);
// reads apply the same involution -> fragments exact, banks spread.
// Stage schedule (1 half = 2 gload_lds/thread): p0:A1^{T+1} p1:B1^{T+1} p2:B0^{T+2} p3:A0^{T+2};
// one vmcnt(4) per tile at p3-end (epilogue: vmcnt(0) at T=14). Never __syncthreads in loop.

#define LHALF 8192   // shorts per 16 KiB half-region

__global__ __launch_bounds__(512, 2) void qkv_gemm256()
{
    __shared__ __attribute__((aligned(16))) short L[8][LHALF]; // [buf*4 + mat*2 + half]

    const int t = threadIdx.x;
    const int lane = t & 63;
    const int w    = t >> 6;          // 0..7
    const int l15  = lane & 15;
    const int qg   = lane >> 4;       // 0..3
    const int wr   = w >> 2;          // 0..1  (M half owned by this wave)
    const int wc   = w & 3;           // 0..3  (N quarter)

    const int bid = blockIdx.x;       // 0..191
    const int mb  = (bid & 15) << 8;  // 16 M tiles
    const int nb  = (bid >> 4) << 8;  // 12 N tiles

    // staging geometry: lane's linear LDS bytes b = w*2048 + j*1024 + lane*16;
    // source coords of u = b ^ (((lane>>5)&1)<<5):
    const int srow = w * 16 + (lane >> 3);                       // + j*8
    const int scol = ((lane & 7) << 3) ^ ((lane >> 5) << 4);     // shorts
    const short* pA0 = g_X + (long)(mb       + srow) * 1024 + scol;
    const short* pA1 = g_X + (long)(mb + 128 + srow) * 1024 + scol;
    const short* pB0 = g_W + (long)(nb       + srow) * 1024 + scol;
    const short* pB1 = g_W + (long)(nb + 128 + srow) * 1024 + scol;
    const int ldst = w * 1024 + lane * 8;                        // shorts; +512 for j=1

#define STAGE(reg_, gp_, kt_) do {                         \
        short* lp_ = &L[(reg_)][ldst];                     \
        GLOAD_LDS((gp_) + (long)(kt_), lp_);               \
        GLOAD_LDS((gp_) + 8192 + (long)(kt_), lp_ + 512);  \
    } while (0)

#define BARRIER() asm volatile("s_barrier" ::: "memory")

    // read-side swizzle: XOR 16 shorts when (row>>2)&1, which equals (l15>>2)&1
    const int axs    = (l15 & 4) << 2;            // 0 or 16 shorts
    const int a_off0 = (qg << 3) ^ axs;           // kk = 0
    const int a_off1 = (32 + (qg << 3)) ^ axs;    // kk = 1
    const int brow   = (wc & 1) * 64;

    f32x4 acc[8][4] = {};

    // prologue: queue order B0^0, A0^0, A1^0, B1^0, B0^1, A0^1 (12 loads)
    STAGE(0*4 + 2 + 0, pB0, 0);
    STAGE(0*4 + 0 + 0, pA0, 0);
    STAGE(0*4 + 0 + 1, pA1, 0);
    STAGE(0*4 + 2 + 1, pB1, 0);
    STAGE(1*4 + 2 + 0, pB0, 64);
    STAGE(1*4 + 0 + 0, pA0, 64);
    asm volatile("s_waitcnt vmcnt(4)" ::: "memory");   // tile0's 4 halves landed
    BARRIER();

    for (int T = 0; T < 16; T++) {
        const int buf = T & 1;
        const short* Ah = L[buf*4 + wr];
        const short* Bh = L[buf*4 + 2 + (wc >> 1)];
        short8 afr[4][2], bfr[4][2];

        // ---------------- p0: read A mi0-3 + B ni0-1; stage A1^{T+1}; MFMA Q(lo,lo)
        #pragma unroll
        for (int mi = 0; mi < 4; mi++) {
            const int rb = (mi*16 + l15) * 64;
            afr[mi][0] = *(const short8*)(Ah + rb + a_off0);
            afr[mi][1] = *(const short8*)(Ah + rb + a_off1);
        }
        #pragma unroll
        for (int ni = 0; ni < 2; ni++) {
            const int rb = (brow + ni*16 + l15) * 64;
            bfr[ni][0] = *(const short8*)(Bh + rb + a_off0);
            bfr[ni][1] = *(const short8*)(Bh + rb + a_off1);
        }
        if (T + 1 < 16) STAGE(((T+1)&1)*4 + 1, pA1, (T+1)*64);
        BARRIER();
        __builtin_amdgcn_s_setprio(1);
        #pragma unroll
        for (int mi = 0; mi < 4; mi++)
            #pragma unroll
            for (int ni = 0; ni < 2; ni++) {
                acc[mi][ni] = __builtin_amdgcn_mfma_f32_16x16x32_bf16(afr[mi][0], bfr[ni][0], acc[mi][ni], 0, 0, 0);
                acc[mi][ni] = __builtin_amdgcn_mfma_f32_16x16x32_bf16(afr[mi][1], bfr[ni][1], acc[mi][ni], 0, 0, 0);
            }
        __builtin_amdgcn_s_setprio(0);
        BARRIER();

        // ---------------- p1: read B ni2-3; stage B1^{T+1}; MFMA Q(lo,hi)
        #pragma unroll
        for (int ni = 2; ni < 4; ni++) {
            const int rb = (brow + ni*16 + l15) * 64;
            bfr[ni][0] = *(const short8*)(Bh + rb + a_off0);
            bfr[ni][1] = *(const short8*)(Bh + rb + a_off1);
        }
        if (T + 1 < 16) STAGE(((T+1)&1)*4 + 2 + 1, pB1, (T+1)*64);
        BARRIER();
        __builtin_amdgcn_s_setprio(1);
        #pragma unroll
        for (int mi = 0; mi < 4; mi++)
            #pragma unroll
            for (int ni = 2; ni < 4; ni++) {
                acc[mi][ni] = __builtin_amdgcn_mfma_f32_16x16x32_bf16(afr[mi][0], bfr[ni][0], acc[mi][ni], 0, 0, 0);
                acc[mi][ni] = __builtin_amdgcn_mfma_f32_16x16x32_bf16(afr[mi][1], bfr[ni][1], acc[mi][ni], 0, 0, 0);
            }
        __builtin_amdgcn_s_setprio(0);
        BARRIER();

        // ---------------- p2: read A mi4-7; stage B0^{T+2}; MFMA Q(hi,hi)
        #pragma unroll
        for (int mi = 0; mi < 4; mi++) {
            const int rb = ((mi + 4)*16 + l15) * 64;
            afr[mi][0] = *(const short8*)(Ah + rb + a_off0);
            afr[mi][1] = *(const short8*)(Ah + rb + a_off1);
        }
        if (T + 2 < 16) STAGE((T&1)*4 + 2 + 0, pB0, (T+2)*64);
        BARRIER();
        __builtin_amdgcn_s_setprio(1);
        #pragma unroll
        for (int mi = 0; mi < 4; mi++)
            #pragma unroll
            for (int ni = 2; ni < 4; ni++) {
                acc[mi+4][ni] = __builtin_amdgcn_mfma_f32_16x16x32_bf16(afr[mi][0], bfr[ni][0], acc[mi+4][ni], 0, 0, 0);
                acc[mi+4][ni] = __builtin_amdgcn_mfma_f32_16x16x32_bf16(afr[mi][1], bfr[ni][1], acc[mi+4][ni], 0, 0, 0);
            }
        __builtin_amdgcn_s_setprio(0);
        BARRIER();

        // ---------------- p3: stage A0^{T+2}; MFMA Q(hi,lo); counted vmcnt; barrier
        if (T + 2 < 16) STAGE((T&1)*4 + 0, pA0, (T+2)*64);
        BARRIER();
        __builtin_amdgcn_s_setprio(1);
        #pragma unroll
        for (int mi = 0; mi < 4; mi++)
            #pragma unroll
            for (int ni = 0; ni < 2; ni++) {
                acc[mi+4][ni] = __builtin_amdgcn_mfma_f32_16x16x32_bf16(afr[mi][0], bfr[ni][0], acc[mi+4][ni], 0, 0, 0);
                acc[mi+4][ni] = __builtin_amdgcn_mfma_f32_16x16x32_bf16(afr[mi][1], bfr[ni][1], acc[mi+4][ni], 0, 0, 0);
            }
        __builtin_amdgcn_s_setprio(0);
        if (T <= 13)      asm volatile("s_waitcnt vmcnt(4)" ::: "memory");
        else if (T == 14) asm volatile("s_waitcnt vmcnt(0)" ::: "memory");
        BARRIER();
    }

    // ---------------- epilogue: bias (+ Q scale), scatter to [B,H,S,DK]
    const int nbase = nb + wc * 64;
    const int z = nbase >> 10;
    short* __restrict__ Out = (z == 0) ? g_Q : ((z == 1) ? g_K : g_V);
    const float scale = (z == 0) ? 0.125f : 1.0f;
    const int rg = qg * 4;
    #pragma unroll
    for (int ni = 0; ni < 4; ni++) {
        const int n = nbase + ni * 16 + l15;
        const int c = n & 1023;
        const float bv_ = bf2f(g_b[z * 1024 + c]);
        const int h = c >> 6, d = c & 63;
        #pragma unroll
        for (int mi = 0; mi < 8; mi++) {
            #pragma unroll
            for (int r = 0; r < 4; r++) {
                const int row = mb + wr * 128 + mi * 16 + rg + r;
                const int bI = row >> 11, s = row & 2047;
                Out[(((long)(bI * NH + h) * S_LEN) + s) * DK + d] = f2bf((acc[mi][ni][r] + bv_) * scale);
            }
        }
    }
#undef STAGE
#undef BARRIER
}

// ---------------- Out-proj (R9 form): 128x64 tiles, BK=32, 512 blocks ---------------
__global__ __launch_bounds__(256) void o_gemm(float* __restrict__ Out)
{
    __shared__ __attribute__((aligned(16))) short As[128 * 32];
    __shared__ __attribute__((aligned(16))) short Bs[64 * 32];

    const short* __restrict__ A = g_AO;
    const short* __restrict__ W = g_W + 3L * W_ELEMS;

    const int t = threadIdx.x;
    const int lane = t & 63;
    const int wid  = t >> 6;
    const int wm = wid & 1, wn = wid >> 1;
    const int l15 = lane & 15;
    const int q8  = (lane >> 4) * 8;
    const int mb = blockIdx.x * 128;
    const int nb = blockIdx.y * 64;

    const long ga0 = (long)(mb + (t >> 2)) * 1024 + (t & 3) * 8;
    const long ga1 = (long)(mb + 64 + (t >> 2)) * 1024 + (t & 3) * 8;
    const long gb0 = (long)(nb + (t >> 2)) * 1024 + (t & 3) * 8;
    short* lA0 = As + t * 8;
    short* lA1 = As + 2048 + t * 8;
    short* lB0 = Bs + t * 8;

    f32x4 acc[4][2] = {};

    for (int k0 = 0; k0 < 1024; k0 += 32) {
        __syncthreads();
        GLOAD_LDS(A + ga0 + k0, lA0);
        GLOAD_LDS(A + ga1 + k0, lA1);
        GLOAD_LDS(W + gb0 + k0, lB0);
        __syncthreads();

        short8 a[4], b[2];
        #pragma unroll
        for (int mt = 0; mt < 4; mt++) a[mt] = *(const short8*)(As + (wm * 64 + mt * 16 + l15) * 32 + q8);
        #pragma unroll
        for (int nt = 0; nt < 2; nt++) b[nt] = *(const short8*)(Bs + (wn * 32 + nt * 16 + l15) * 32 + q8);
        #pragma unroll
        for (int mt = 0; mt < 4; mt++)
            #pragma unroll
            for (int nt = 0; nt < 2; nt++)
                acc[mt][nt] = __builtin_amdgcn_mfma_f32_16x16x32_bf16(a[mt], b[nt], acc[mt][nt], 0, 0, 0);
    }

    const int rg = (lane >> 4) * 4;
    #pragma unroll
    for (int nt = 0; nt < 2; nt++) {
        const int col = nb + wn * 32 + nt * 16 + l15;
        const float bv_ = bf2f(g_b[3 * 1024 + col]);
        #pragma unroll
        for (int mt = 0; mt < 4; mt++) {
            #pragma unroll
            for (int r = 0; r < 4; r++) {
                const int row = mb + wm * 64 + mt * 16 + rg + r;
                Out[(long)row * 1024 + col] = acc[mt][nt][r] + bv_;
            }
        }
    }
}

// ------- Banded attention: 64 q/block, online softmax, K prefetch, XCD swizzle ------
// bid = qt*32 + head  =>  bid%8 == head%8: one head's q-tiles share an XCD L2.
#define VT_PAD 328   // 656 B = 164 dw; 164%32=4 -> 4-bank row skew (2-way, free)

__global__ __launch_bounds__(256) void attn_kernel()
{
    __shared__ __attribute__((aligned(16))) short Vt[64][VT_PAD];   // [dim][key-kb0]
    __shared__ __attribute__((aligned(16))) short Pl[4][16][72];    // per-wave P [row][key]

    const int bid  = blockIdx.x;
    const int head = bid & 31;          // b*16+h
    const int qt   = bid >> 5;          // 0..31
    const int h = head & 15, b = head >> 4;
    const int qbase = qt * 64;

    const int lane = threadIdx.x & 63;
    const int w    = threadIdx.x >> 6;
    const int l15  = lane & 15;
    const int qg   = lane >> 4;
    const int q8   = qg * 8;

    const long hoff = (long)(b * NH + h) * S_LEN * DK;
    const short* __restrict__ Qh = g_Q + hoff;
    const short* __restrict__ Kh = g_K + hoff;
    const short* __restrict__ Vh = g_V + hoff;

    const int lo  = qbase - (BANDW - 1);
    const int kc0 = (lo < 0 ? 0 : lo) >> 6;
    int hi = qbase + 64 + (BANDW - 1);
    if (hi > S_LEN) hi = S_LEN;
    const int kc1 = (hi + 63) >> 6;
    const int kb0 = kc0 * 64;
    const int n_keys = (kc1 - kc0) * 64;   // <= 320

    // Q fragments (already pre-scaled by 1/8 at projection)
    const short* qp = Qh + (long)(qbase + w * 16 + l15) * DK + q8;
    const short8 aq0 = *(const short8*)(qp);
    const short8 aq1 = *(const short8*)(qp + 32);

    // ---- stage whole-band V^T, two keys per thread, paired 4B writes ----
    const int npairs = n_keys >> 1;
    for (int u = threadIdx.x; u < npairs; u += 256) {
        const short* vp0 = Vh + (long)(kb0 + 2 * u) * DK;
        #pragma unroll
        for (int tq = 0; tq < 8; tq++) {
            const short8 v0 = *(const short8*)(vp0 + tq * 8);
            const short8 v1 = *(const short8*)(vp0 + DK + tq * 8);
            #pragma unroll
            for (int e = 0; e < 8; e++) {
                const int pk = (int)(unsigned short)v0[e] | ((int)(unsigned short)v1[e] << 16);
                *(int*)&Vt[tq * 8 + e][2 * u] = pk;
            }
        }
    }
    __syncthreads();   // only block barrier

    // ---- prefetch first chunk's K fragments ----
    short8 nk0[4], nk1[4];
    #pragma unroll
    for (int nt = 0; nt < 4; nt++) {
        const short* kp = Kh + (long)(kb0 + nt * 16 + l15) * DK + q8;
        nk0[nt] = *(const short8*)(kp);
        nk1[nt] = *(const short8*)(kp + 32);
    }

    f32x4 o[4] = {};
    float m_r[4], l_r[4];
    #pragma unroll
    for (int r = 0; r < 4; r++) { m_r[r] = -1e30f; l_r[r] = 0.f; }

    for (int kc = kc0; kc < kc1; kc++) {
        const int kb = kc * 64;
        const int kloc = kb - kb0;

        // consume prefetched K; immediately issue next chunk's loads
        short8 bk0[4], bk1[4];
        #pragma unroll
        for (int nt = 0; nt < 4; nt++) { bk0[nt] = nk0[nt]; bk1[nt] = nk1[nt]; }
        if (kc + 1 < kc1) {
            const int kbn = kb + 64;
            #pragma unroll
            for (int nt = 0; nt < 4; nt++) {
                const short* kp = Kh + (long)(kbn + nt * 16 + l15) * DK + q8;
                nk0[nt] = *(const short8*)(kp);
                nk1[nt] = *(const short8*)(kp + 32);
            }
        }

        // S-tile = (Q/8) K^T
        f32x4 sc[4];
        #pragma unroll
        for (int nt = 0; nt < 4; nt++) {
            f32x4 z = {};
            z = __builtin_amdgcn_mfma_f32_16x16x32_bf16(aq0, bk0[nt], z, 0, 0, 0);
            z = __builtin_amdgcn_mfma_f32_16x16x32_bf16(aq1, bk1[nt], z, 0, 0, 0);
            sc[nt] = z;
        }

        float pv[4][4];
        float mx[4] = {-1e30f, -1e30f, -1e30f, -1e30f};
        if (kb == qbase) {
            // diagonal chunk: fully inside band, skip mask arithmetic
            #pragma unroll
            for (int nt = 0; nt < 4; nt++)
                #pragma unroll
                for (int r = 0; r < 4; r++) {
                    pv[nt][r] = sc[nt][r];
                    mx[r] = fmaxf(mx[r], sc[nt][r]);
                }
        } else {
            #pragma unroll
            for (int nt = 0; nt < 4; nt++) {
                const int kg = kb + nt * 16 + l15;
                #pragma unroll
                for (int r = 0; r < 4; r++) {
                    const int qI = qbase + w * 16 + qg * 4 + r;
                    int dlt = qI - kg; if (dlt < 0) dlt = -dlt;
                    const float v = (dlt < BANDW) ? sc[nt][r] : -1e30f;
                    pv[nt][r] = v;
                    mx[r] = fmaxf(mx[r], v);
                }
            }
        }
        #pragma unroll
        for (int mk = 1; mk < 16; mk <<= 1)
            #pragma unroll
            for (int r = 0; r < 4; r++) mx[r] = fmaxf(mx[r], __shfl_xor(mx[r], mk, 64));

        float alpha[4], lnew[4];
        #pragma unroll
        for (int r = 0; r < 4; r++) {
            const float mn = fmaxf(m_r[r], mx[r]);
            alpha[r] = __builtin_exp2f((m_r[r] - mn) * 1.44269504f);
            m_r[r] = mn;
            lnew[r] = 0.f;
        }
        #pragma unroll
        for (int nt = 0; nt < 4; nt++)
            #pragma unroll
            for (int r = 0; r < 4; r++) {
                const float p = (pv[nt][r] > -0.5e30f)
                    ? __builtin_exp2f((pv[nt][r] - m_r[r]) * 1.44269504f) : 0.f;
                pv[nt][r] = p;
                lnew[r] += p;
            }
        #pragma unroll
        for (int mk = 1; mk < 16; mk <<= 1)
            #pragma unroll
            for (int r = 0; r < 4; r++) lnew[r] += __shfl_xor(lnew[r], mk, 64);
        #pragma unroll
        for (int r = 0; r < 4; r++) l_r[r] = l_r[r] * alpha[r] + lnew[r];
        #pragma unroll
        for (int nt2 = 0; nt2 < 4; nt2++)
            #pragma unroll
            for (int r = 0; r < 4; r++) o[nt2][r] *= alpha[r];

        // P (C layout) -> per-wave LDS -> A layout (lgkm wait only)
        #pragma unroll
        for (int nt = 0; nt < 4; nt++)
            #pragma unroll
            for (int r = 0; r < 4; r++)
                Pl[w][qg * 4 + r][nt * 16 + l15] = f2bf(pv[nt][r]);
        asm volatile("s_waitcnt lgkmcnt(0)" ::: "memory");
        const short8 ap0 = *(const short8*)(&Pl[w][l15][q8]);
        const short8 ap1 = *(const short8*)(&Pl[w][l15][32 + q8]);

        #pragma unroll
        for (int nt2 = 0; nt2 < 4; nt2++) {
            const short* vrow = &Vt[nt2 * 16 + l15][kloc];
            const short8 bv0 = *(const short8*)(vrow + q8);
            const short8 bv1 = *(const short8*)(vrow + 32 + q8);
            o[nt2] = __builtin_amdgcn_mfma_f32_16x16x32_bf16(ap0, bv0, o[nt2], 0, 0, 0);
            o[nt2] = __builtin_amdgcn_mfma_f32_16x16x32_bf16(ap1, bv1, o[nt2], 0, 0, 0);
        }
    }

    #pragma unroll
    for (int nt2 = 0; nt2 < 4; nt2++)
        #pragma unroll
        for (int r = 0; r < 4; r++) {
            const int qI = qbase + w * 16 + qg * 4 + r;
            const int d = nt2 * 16 + l15;
            g_AO[((long)b * S_LEN + qI) * 1024 + h * DK + d] = f2bf(o[nt2][r] / l_r[r]);
        }
}

extern "C" void kernel_launch(void* const* d_in, const int* in_sizes, int n_in,
                              void* d_out, int out_size, void* d_ws, size_t ws_size,
                              hipStream_t stream) {
    float* out = (float*)d_out;

    convert_all<<<(TOTC + 255) / 256, 256, 0, stream>>>(
        d_in[0], d_in[1], d_in[2], d_in[3], d_in[4], d_in[5], d_in[6], d_in[7], d_in[8]);
    qkv_gemm256<<<dim3(192), 512, 0, stream>>>();
    attn_kernel<<<dim3(2 * NH * (S_LEN / 64)), 256, 0, stream>>>();
    o_gemm<<<dim3(32, 16), 256, 0, stream>>>(out);
}

// Round 2
// 173.829 us; speedup vs baseline: 1.0582x; 1.0582x over previous
//
#include <hip/hip_runtime.h>
#include <hip/hip_bf16.h>

// B=2, S=2048, D=1024, H=16, DK=64, BAND=100. Inputs f32 (auto-detect; bf16 fallback).
// Output f32. R11: fix qkv_gemm256 LDS swizzle to 3-bit XOR (byte ^= (row&7)<<4):
// R10's 1-bit swizzle left a 4-way bank conflict (2.36M cycles). Also coalesce the
// epilogue stores (ni innermost -> full 128B lines). Rest unchanged from R10.

typedef __attribute__((ext_vector_type(8))) short short8;
typedef __attribute__((ext_vector_type(4))) float f32x4;

#define S_LEN 2048
#define NH 16
#define DK 64
#define BANDW 100

#define X_ELEMS   (2 * S_LEN * 1024)
#define W_ELEMS   (1024 * 1024)
#define QKV_ELEMS (2 * NH * S_LEN * DK)
#define AO_ELEMS  (2 * S_LEN * 1024)

__device__ __attribute__((aligned(256))) short g_X[X_ELEMS];
__device__ __attribute__((aligned(256))) short g_W[4 * W_ELEMS];   // Wq|Wk|Wv|Wo
__device__ __attribute__((aligned(256))) short g_b[4 * 1024];      // bq|bk|bv|bo
__device__ __attribute__((aligned(256))) short g_Q[QKV_ELEMS];     // pre-scaled by 1/8
__device__ __attribute__((aligned(256))) short g_K[QKV_ELEMS];
__device__ __attribute__((aligned(256))) short g_V[QKV_ELEMS];     // row-major [B,H,S,DK]
__device__ __attribute__((aligned(256))) short g_AO[AO_ELEMS];

__device__ __forceinline__ float bf2f(short u) {
    unsigned x = ((unsigned)(unsigned short)u) << 16;
    return __builtin_bit_cast(float, x);
}
__device__ __forceinline__ short f2bf(float f) {
    unsigned x = __builtin_bit_cast(unsigned, f);
    unsigned r = (x + 0x7fffu + ((x >> 16) & 1u)) >> 16;
    return (short)r;
}

#define GLOAD_LDS(gp, lp) \
    __builtin_amdgcn_global_load_lds( \
        (const __attribute__((address_space(1))) void*)(gp), \
        (__attribute__((address_space(3))) void*)(lp), 16, 0, 0)

// ---------------- Fused detect + convert (R9 form) ----------------
#define XC   (X_ELEMS / 8)
#define WC   (W_ELEMS / 8)
#define BC   (1024 / 8)
#define TOTC (XC + 4 * WC + 4 * BC)

__global__ __launch_bounds__(256) void convert_all(
    const void* __restrict__ x,
    const void* __restrict__ w0, const void* __restrict__ b0,
    const void* __restrict__ w1, const void* __restrict__ b1,
    const void* __restrict__ w2, const void* __restrict__ b2,
    const void* __restrict__ w3, const void* __restrict__ b3)
{
    __shared__ int cnt[256];
    {
        const unsigned* xw = (const unsigned*)x;
        int local = 0;
        #pragma unroll
        for (int i = 0; i < 4; i++) {
            unsigned wv = xw[threadIdx.x * 4 + i];
            unsigned e = (wv >> 7) & 0xFF;
            if (e >= 100 && e <= 140) local++;
        }
        cnt[threadIdx.x] = local;
    }
    __syncthreads();
    for (int s = 128; s > 0; s >>= 1) {
        if (threadIdx.x < s) cnt[threadIdx.x] += cnt[threadIdx.x + s];
        __syncthreads();
    }
    const int is_bf16 = (cnt[0] > 512);

    long i = (long)blockIdx.x * 256 + threadIdx.x;
    if (i >= TOTC) return;

    const void* src; short* dst; long off;
    if (i < XC)                { src = x;  dst = g_X;              off = i; }
    else if ((i -= XC) < WC)   { src = w0; dst = g_W + 0L*W_ELEMS; off = i; }
    else if ((i -= WC) < WC)   { src = w1; dst = g_W + 1L*W_ELEMS; off = i; }
    else if ((i -= WC) < WC)   { src = w2; dst = g_W + 2L*W_ELEMS; off = i; }
    else if ((i -= WC) < WC)   { src = w3; dst = g_W + 3L*W_ELEMS; off = i; }
    else if ((i -= WC) < BC)   { src = b0; dst = g_b + 0*1024;     off = i; }
    else if ((i -= BC) < BC)   { src = b1; dst = g_b + 1*1024;     off = i; }
    else if ((i -= BC) < BC)   { src = b2; dst = g_b + 2*1024;     off = i; }
    else                       { src = b3; dst = g_b + 3*1024;     off = i - BC; }

    if (is_bf16) {
        ((short8*)dst)[off] = ((const short8*)src)[off];
    } else {
        const float* s = (const float*)src + off * 8;
        short8 o;
        #pragma unroll
        for (int e = 0; e < 8; e++) o[e] = f2bf(s[e]);
        ((short8*)dst)[off] = o;
    }
}

// ---------------- Fused QKV GEMM: 256x256 tile, BK=64, 8-wave 8-phase ----------------
// M=4096 (B*S), N=3072 (q|k|v), K=1024. Out[m][n] = sum_k X[m][k]*W[n][k].
// LDS: 2 dbuf x {A,B} x 2 halves x [128][64] bf16 = 128 KiB.
// Swizzle (3-bit, G4-derived): LDS byte b of a region holds global element
// u = b ^ ((row(b)&7)<<4), row(b)=b>>7. Stage side: dest linear, source chunk
// (lane&7)^(lane>>3). Read side: chunk c^(fragrow&7). 8 lanes/slot x 8 slots ->
// conflict-free. Stage schedule: p0:A1^{T+1} p1:B1^{T+1} p2:B0^{T+2} p3:A0^{T+2};
// one vmcnt(4) per tile at p3-end (epilogue drain vmcnt(0) at T=14).

#define LHALF 8192   // shorts per 16 KiB half-region

__global__ __launch_bounds__(512, 2) void qkv_gemm256()
{
    __shared__ __attribute__((aligned(16))) short L[8][LHALF]; // [buf*4 + mat*2 + half]

    const int t = threadIdx.x;
    const int lane = t & 63;
    const int w    = t >> 6;          // 0..7
    const int l15  = lane & 15;
    const int qg   = lane >> 4;       // 0..3
    const int wr   = w >> 2;          // 0..1  (M half owned by this wave)
    const int wc   = w & 3;           // 0..3  (N quarter)

    const int bid = blockIdx.x;       // 0..191
    const int mb  = (bid & 15) << 8;  // 16 M tiles
    const int nb  = (bid >> 4) << 8;  // 12 N tiles

    // staging geometry: lane's linear LDS bytes b = w*2048 + j*1024 + lane*16;
    // region row = w*16 + j*8 + (lane>>3); row&7 = lane>>3.
    // source chunk = (lane&7) ^ (lane>>3)  (16B chunks within the 128B row)
    const int srow = w * 16 + (lane >> 3);                        // + j*8
    const int scol = (((lane & 7) ^ (lane >> 3)) << 3);           // shorts
    const short* pA0 = g_X + (long)(mb       + srow) * 1024 + scol;
    const short* pA1 = g_X + (long)(mb + 128 + srow) * 1024 + scol;
    const short* pB0 = g_W + (long)(nb       + srow) * 1024 + scol;
    const short* pB1 = g_W + (long)(nb + 128 + srow) * 1024 + scol;
    const int ldst = w * 1024 + lane * 8;                         // shorts; +512 for j=1

#define STAGE(reg_, gp_, kt_) do {                         \
        short* lp_ = &L[(reg_)][ldst];                     \
        GLOAD_LDS((gp_) + (long)(kt_), lp_);               \
        GLOAD_LDS((gp_) + 8192 + (long)(kt_), lp_ + 512);  \
    } while (0)

#define BARRIER() asm volatile("s_barrier" ::: "memory")

    // read-side swizzle: fragment row = (..16-mult..) + l15 -> row&7 = l15&7
    const int axs    = (l15 & 7) << 3;            // XOR, in shorts (chunk ^ row&7)
    const int a_off0 = (qg << 3) ^ axs;           // kk = 0 (global chunks 0-3)
    const int a_off1 = (32 + (qg << 3)) ^ axs;    // kk = 1 (global chunks 4-7)
    const int brow   = (wc & 1) * 64;

    f32x4 acc[8][4] = {};

    // prologue: queue order B0^0, A0^0, A1^0, B1^0, B0^1, A0^1 (12 loads)
    STAGE(0*4 + 2 + 0, pB0, 0);
    STAGE(0*4 + 0 + 0, pA0, 0);
    STAGE(0*4 + 0 + 1, pA1, 0);
    STAGE(0*4 + 2 + 1, pB1, 0);
    STAGE(1*4 + 2 + 0, pB0, 64);
    STAGE(1*4 + 0 + 0, pA0, 64);
    asm volatile("s_waitcnt vmcnt(4)" ::: "memory");   // tile0's 4 halves landed
    BARRIER();

    for (int T = 0; T < 16; T++) {
        const int buf = T & 1;
        const short* Ah = L[buf*4 + wr];
        const short* Bh = L[buf*4 + 2 + (wc >> 1)];
        short8 afr[4][2], bfr[4][2];

        // ---------------- p0: read A mi0-3 + B ni0-1; stage A1^{T+1}; MFMA Q(lo,lo)
        #pragma unroll
        for (int mi = 0; mi < 4; mi++) {
            const int rb = (mi*16 + l15) * 64;
            afr[mi][0] = *(const short8*)(Ah + rb + a_off0);
            afr[mi][1] = *(const short8*)(Ah + rb + a_off1);
        }
        #pragma unroll
        for (int ni = 0; ni < 2; ni++) {
            const int rb = (brow + ni*16 + l15) * 64;
            bfr[ni][0] = *(const short8*)(Bh + rb + a_off0);
            bfr[ni][1] = *(const short8*)(Bh + rb + a_off1);
        }
        if (T + 1 < 16) STAGE(((T+1)&1)*4 + 1, pA1, (T+1)*64);
        BARRIER();
        __builtin_amdgcn_s_setprio(1);
        #pragma unroll
        for (int mi = 0; mi < 4; mi++)
            #pragma unroll
            for (int ni = 0; ni < 2; ni++) {
                acc[mi][ni] = __builtin_amdgcn_mfma_f32_16x16x32_bf16(afr[mi][0], bfr[ni][0], acc[mi][ni], 0, 0, 0);
                acc[mi][ni] = __builtin_amdgcn_mfma_f32_16x16x32_bf16(afr[mi][1], bfr[ni][1], acc[mi][ni], 0, 0, 0);
            }
        __builtin_amdgcn_s_setprio(0);
        BARRIER();

        // ---------------- p1: read B ni2-3; stage B1^{T+1}; MFMA Q(lo,hi)
        #pragma unroll
        for (int ni = 2; ni < 4; ni++) {
            const int rb = (brow + ni*16 + l15) * 64;
            bfr[ni][0] = *(const short8*)(Bh + rb + a_off0);
            bfr[ni][1] = *(const short8*)(Bh + rb + a_off1);
        }
        if (T + 1 < 16) STAGE(((T+1)&1)*4 + 2 + 1, pB1, (T+1)*64);
        BARRIER();
        __builtin_amdgcn_s_setprio(1);
        #pragma unroll
        for (int mi = 0; mi < 4; mi++)
            #pragma unroll
            for (int ni = 2; ni < 4; ni++) {
                acc[mi][ni] = __builtin_amdgcn_mfma_f32_16x16x32_bf16(afr[mi][0], bfr[ni][0], acc[mi][ni], 0, 0, 0);
                acc[mi][ni] = __builtin_amdgcn_mfma_f32_16x16x32_bf16(afr[mi][1], bfr[ni][1], acc[mi][ni], 0, 0, 0);
            }
        __builtin_amdgcn_s_setprio(0);
        BARRIER();

        // ---------------- p2: read A mi4-7; stage B0^{T+2}; MFMA Q(hi,hi)
        #pragma unroll
        for (int mi = 0; mi < 4; mi++) {
            const int rb = ((mi + 4)*16 + l15) * 64;
            afr[mi][0] = *(const short8*)(Ah + rb + a_off0);
            afr[mi][1] = *(const short8*)(Ah + rb + a_off1);
        }
        if (T + 2 < 16) STAGE((T&1)*4 + 2 + 0, pB0, (T+2)*64);
        BARRIER();
        __builtin_amdgcn_s_setprio(1);
        #pragma unroll
        for (int mi = 0; mi < 4; mi++)
            #pragma unroll
            for (int ni = 2; ni < 4; ni++) {
                acc[mi+4][ni] = __builtin_amdgcn_mfma_f32_16x16x32_bf16(afr[mi][0], bfr[ni][0], acc[mi+4][ni], 0, 0, 0);
                acc[mi+4][ni] = __builtin_amdgcn_mfma_f32_16x16x32_bf16(afr[mi][1], bfr[ni][1], acc[mi+4][ni], 0, 0, 0);
            }
        __builtin_amdgcn_s_setprio(0);
        BARRIER();

        // ---------------- p3: stage A0^{T+2}; MFMA Q(hi,lo); counted vmcnt; barrier
        if (T + 2 < 16) STAGE((T&1)*4 + 0, pA0, (T+2)*64);
        BARRIER();
        __builtin_amdgcn_s_setprio(1);
        #pragma unroll
        for (int mi = 0; mi < 4; mi++)
            #pragma unroll
            for (int ni = 0; ni < 2; ni++) {
                acc[mi+4][ni] = __builtin_amdgcn_mfma_f32_16x16x32_bf16(afr[mi][0], bfr[ni][0], acc[mi+4][ni], 0, 0, 0);
                acc[mi+4][ni] = __builtin_amdgcn_mfma_f32_16x16x32_bf16(afr[mi][1], bfr[ni][1], acc[mi+4][ni], 0, 0, 0);
            }
        __builtin_amdgcn_s_setprio(0);
        if (T <= 13)      asm volatile("s_waitcnt vmcnt(4)" ::: "memory");
        else if (T == 14) asm volatile("s_waitcnt vmcnt(0)" ::: "memory");
        BARRIER();
    }

    // ------- epilogue: bias (+ Q scale); ni innermost so each 128B line completes -------
    const int nbase = nb + wc * 64;       // 64-aligned, single z and single h per wave
    const int z = nbase >> 10;
    short* __restrict__ Out = (z == 0) ? g_Q : ((z == 1) ? g_K : g_V);
    const float scale = (z == 0) ? 0.125f : 1.0f;
    const int c0 = nbase & 1023;
    const int h = c0 >> 6;                // d = ni*16 + l15 (c0&63 == 0)
    float bv4[4];
    #pragma unroll
    for (int ni = 0; ni < 4; ni++) bv4[ni] = bf2f(g_b[z * 1024 + c0 + ni * 16 + l15]);
    const int rg = qg * 4;
    #pragma unroll
    for (int mi = 0; mi < 8; mi++) {
        #pragma unroll
        for (int r = 0; r < 4; r++) {
            const int row = mb + wr * 128 + mi * 16 + rg + r;
            const int bI = row >> 11, s = row & 2047;
            short* op = Out + (((long)(bI * NH + h) * S_LEN) + s) * DK;
            #pragma unroll
            for (int ni = 0; ni < 4; ni++)
                op[ni * 16 + l15] = f2bf((acc[mi][ni][r] + bv4[ni]) * scale);
        }
    }
#undef STAGE
#undef BARRIER
}

// ---------------- Out-proj (R9 form): 128x64 tiles, BK=32, 512 blocks ---------------
__global__ __launch_bounds__(256) void o_gemm(float* __restrict__ Out)
{
    __shared__ __attribute__((aligned(16))) short As[128 * 32];
    __shared__ __attribute__((aligned(16))) short Bs[64 * 32];

    const short* __restrict__ A = g_AO;
    const short* __restrict__ W = g_W + 3L * W_ELEMS;

    const int t = threadIdx.x;
    const int lane = t & 63;
    const int wid  = t >> 6;
    const int wm = wid & 1, wn = wid >> 1;
    const int l15 = lane & 15;
    const int q8  = (lane >> 4) * 8;
    const int mb = blockIdx.x * 128;
    const int nb = blockIdx.y * 64;

    const long ga0 = (long)(mb + (t >> 2)) * 1024 + (t & 3) * 8;
    const long ga1 = (long)(mb + 64 + (t >> 2)) * 1024 + (t & 3) * 8;
    const long gb0 = (long)(nb + (t >> 2)) * 1024 + (t & 3) * 8;
    short* lA0 = As + t * 8;
    short* lA1 = As + 2048 + t * 8;
    short* lB0 = Bs + t * 8;

    f32x4 acc[4][2] = {};

    for (int k0 = 0; k0 < 1024; k0 += 32) {
        __syncthreads();
        GLOAD_LDS(A + ga0 + k0, lA0);
        GLOAD_LDS(A + ga1 + k0, lA1);
        GLOAD_LDS(W + gb0 + k0, lB0);
        __syncthreads();

        short8 a[4], b[2];
        #pragma unroll
        for (int mt = 0; mt < 4; mt++) a[mt] = *(const short8*)(As + (wm * 64 + mt * 16 + l15) * 32 + q8);
        #pragma unroll
        for (int nt = 0; nt < 2; nt++) b[nt] = *(const short8*)(Bs + (wn * 32 + nt * 16 + l15) * 32 + q8);
        #pragma unroll
        for (int mt = 0; mt < 4; mt++)
            #pragma unroll
            for (int nt = 0; nt < 2; nt++)
                acc[mt][nt] = __builtin_amdgcn_mfma_f32_16x16x32_bf16(a[mt], b[nt], acc[mt][nt], 0, 0, 0);
    }

    const int rg = (lane >> 4) * 4;
    #pragma unroll
    for (int nt = 0; nt < 2; nt++) {
        const int col = nb + wn * 32 + nt * 16 + l15;
        const float bv_ = bf2f(g_b[3 * 1024 + col]);
        #pragma unroll
        for (int mt = 0; mt < 4; mt++) {
            #pragma unroll
            for (int r = 0; r < 4; r++) {
                const int row = mb + wm * 64 + mt * 16 + rg + r;
                Out[(long)row * 1024 + col] = acc[mt][nt][r] + bv_;
            }
        }
    }
}

// ------- Banded attention: 64 q/block, online softmax, K prefetch, XCD swizzle ------
// bid = qt*32 + head  =>  bid%8 == head%8: one head's q-tiles share an XCD L2.
#define VT_PAD 328   // 656 B = 164 dw; 164%32=4 -> 4-bank row skew (2-way, free)

__global__ __launch_bounds__(256) void attn_kernel()
{
    __shared__ __attribute__((aligned(16))) short Vt[64][VT_PAD];   // [dim][key-kb0]
    __shared__ __attribute__((aligned(16))) short Pl[4][16][72];    // per-wave P [row][key]

    const int bid  = blockIdx.x;
    const int head = bid & 31;          // b*16+h
    const int qt   = bid >> 5;          // 0..31
    const int h = head & 15, b = head >> 4;
    const int qbase = qt * 64;

    const int lane = threadIdx.x & 63;
    const int w    = threadIdx.x >> 6;
    const int l15  = lane & 15;
    const int qg   = lane >> 4;
    const int q8   = qg * 8;

    const long hoff = (long)(b * NH + h) * S_LEN * DK;
    const short* __restrict__ Qh = g_Q + hoff;
    const short* __restrict__ Kh = g_K + hoff;
    const short* __restrict__ Vh = g_V + hoff;

    const int lo  = qbase - (BANDW - 1);
    const int kc0 = (lo < 0 ? 0 : lo) >> 6;
    int hi = qbase + 64 + (BANDW - 1);
    if (hi > S_LEN) hi = S_LEN;
    const int kc1 = (hi + 63) >> 6;
    const int kb0 = kc0 * 64;
    const int n_keys = (kc1 - kc0) * 64;   // <= 320

    // Q fragments (already pre-scaled by 1/8 at projection)
    const short* qp = Qh + (long)(qbase + w * 16 + l15) * DK + q8;
    const short8 aq0 = *(const short8*)(qp);
    const short8 aq1 = *(const short8*)(qp + 32);

    // ---- stage whole-band V^T, two keys per thread, paired 4B writes ----
    const int npairs = n_keys >> 1;
    for (int u = threadIdx.x; u < npairs; u += 256) {
        const short* vp0 = Vh + (long)(kb0 + 2 * u) * DK;
        #pragma unroll
        for (int tq = 0; tq < 8; tq++) {
            const short8 v0 = *(const short8*)(vp0 + tq * 8);
            const short8 v1 = *(const short8*)(vp0 + DK + tq * 8);
            #pragma unroll
            for (int e = 0; e < 8; e++) {
                const int pk = (int)(unsigned short)v0[e] | ((int)(unsigned short)v1[e] << 16);
                *(int*)&Vt[tq * 8 + e][2 * u] = pk;
            }
        }
    }
    __syncthreads();   // only block barrier

    // ---- prefetch first chunk's K fragments ----
    short8 nk0[4], nk1[4];
    #pragma unroll
    for (int nt = 0; nt < 4; nt++) {
        const short* kp = Kh + (long)(kb0 + nt * 16 + l15) * DK + q8;
        nk0[nt] = *(const short8*)(kp);
        nk1[nt] = *(const short8*)(kp + 32);
    }

    f32x4 o[4] = {};
    float m_r[4], l_r[4];
    #pragma unroll
    for (int r = 0; r < 4; r++) { m_r[r] = -1e30f; l_r[r] = 0.f; }

    for (int kc = kc0; kc < kc1; kc++) {
        const int kb = kc * 64;
        const int kloc = kb - kb0;

        // consume prefetched K; immediately issue next chunk's loads
        short8 bk0[4], bk1[4];
        #pragma unroll
        for (int nt = 0; nt < 4; nt++) { bk0[nt] = nk0[nt]; bk1[nt] = nk1[nt]; }
        if (kc + 1 < kc1) {
            const int kbn = kb + 64;
            #pragma unroll
            for (int nt = 0; nt < 4; nt++) {
                const short* kp = Kh + (long)(kbn + nt * 16 + l15) * DK + q8;
                nk0[nt] = *(const short8*)(kp);
                nk1[nt] = *(const short8*)(kp + 32);
            }
        }

        // S-tile = (Q/8) K^T
        f32x4 sc[4];
        #pragma unroll
        for (int nt = 0; nt < 4; nt++) {
            f32x4 z = {};
            z = __builtin_amdgcn_mfma_f32_16x16x32_bf16(aq0, bk0[nt], z, 0, 0, 0);
            z = __builtin_amdgcn_mfma_f32_16x16x32_bf16(aq1, bk1[nt], z, 0, 0, 0);
            sc[nt] = z;
        }

        float pv[4][4];
        float mx[4] = {-1e30f, -1e30f, -1e30f, -1e30f};
        if (kb == qbase) {
            // diagonal chunk: fully inside band, skip mask arithmetic
            #pragma unroll
            for (int nt = 0; nt < 4; nt++)
                #pragma unroll
                for (int r = 0; r < 4; r++) {
                    pv[nt][r] = sc[nt][r];
                    mx[r] = fmaxf(mx[r], sc[nt][r]);
                }
        } else {
            #pragma unroll
            for (int nt = 0; nt < 4; nt++) {
                const int kg = kb + nt * 16 + l15;
                #pragma unroll
                for (int r = 0; r < 4; r++) {
                    const int qI = qbase + w * 16 + qg * 4 + r;
                    int dlt = qI - kg; if (dlt < 0) dlt = -dlt;
                    const float v = (dlt < BANDW) ? sc[nt][r] : -1e30f;
                    pv[nt][r] = v;
                    mx[r] = fmaxf(mx[r], v);
                }
            }
        }
        #pragma unroll
        for (int mk = 1; mk < 16; mk <<= 1)
            #pragma unroll
            for (int r = 0; r < 4; r++) mx[r] = fmaxf(mx[r], __shfl_xor(mx[r], mk, 64));

        float alpha[4], lnew[4];
        #pragma unroll
        for (int r = 0; r < 4; r++) {
            const float mn = fmaxf(m_r[r], mx[r]);
            alpha[r] = __builtin_exp2f((m_r[r] - mn) * 1.44269504f);
            m_r[r] = mn;
            lnew[r] = 0.f;
        }
        #pragma unroll
        for (int nt = 0; nt < 4; nt++)
            #pragma unroll
            for (int r = 0; r < 4; r++) {
                const float p = (pv[nt][r] > -0.5e30f)
                    ? __builtin_exp2f((pv[nt][r] - m_r[r]) * 1.44269504f) : 0.f;
                pv[nt][r] = p;
                lnew[r] += p;
            }
        #pragma unroll
        for (int mk = 1; mk < 16; mk <<= 1)
            #pragma unroll
            for (int r = 0; r < 4; r++) lnew[r] += __shfl_xor(lnew[r], mk, 64);
        #pragma unroll
        for (int r = 0; r < 4; r++) l_r[r] = l_r[r] * alpha[r] + lnew[r];
        #pragma unroll
        for (int nt2 = 0; nt2 < 4; nt2++)
            #pragma unroll
            for (int r = 0; r < 4; r++) o[nt2][r] *= alpha[r];

        // P (C layout) -> per-wave LDS -> A layout (lgkm wait only)
        #pragma unroll
        for (int nt = 0; nt < 4; nt++)
            #pragma unroll
            for (int r = 0; r < 4; r++)
                Pl[w][qg * 4 + r][nt * 16 + l15] = f2bf(pv[nt][r]);
        asm volatile("s_waitcnt lgkmcnt(0)" ::: "memory");
        const short8 ap0 = *(const short8*)(&Pl[w][l15][q8]);
        const short8 ap1 = *(const short8*)(&Pl[w][l15][32 + q8]);

        #pragma unroll
        for (int nt2 = 0; nt2 < 4; nt2++) {
            const short* vrow = &Vt[nt2 * 16 + l15][kloc];
            const short8 bv0 = *(const short8*)(vrow + q8);
            const short8 bv1 = *(const short8*)(vrow + 32 + q8);
            o[nt2] = __builtin_amdgcn_mfma_f32_16x16x32_bf16(ap0, bv0, o[nt2], 0, 0, 0);
            o[nt2] = __builtin_amdgcn_mfma_f32_16x16x32_bf16(ap1, bv1, o[nt2], 0, 0, 0);
        }
    }

    #pragma unroll
    for (int nt2 = 0; nt2 < 4; nt2++)
        #pragma unroll
        for (int r = 0; r < 4; r++) {
            const int qI = qbase + w * 16 + qg * 4 + r;
            const int d = nt2 * 16 + l15;
            g_AO[((long)b * S_LEN + qI) * 1024 + h * DK + d] = f2bf(o[nt2][r] / l_r[r]);
        }
}

extern "C" void kernel_launch(void* const* d_in, const int* in_sizes, int n_in,
                              void* d_out, int out_size, void* d_ws, size_t ws_size,
                              hipStream_t stream) {
    float* out = (float*)d_out;

    convert_all<<<(TOTC + 255) / 256, 256, 0, stream>>>(
        d_in[0], d_in[1], d_in[2], d_in[3], d_in[4], d_in[5], d_in[6], d_in[7], d_in[8]);
    qkv_gemm256<<<dim3(192), 512, 0, stream>>>();
    attn_kernel<<<dim3(2 * NH * (S_LEN / 64)), 256, 0, stream>>>();
    o_gemm<<<dim3(32, 16), 256, 0, stream>>>(out);
}